// Round 4
// baseline (276.417 us; speedup 1.0000x reference)
//
#include <hip/hip_runtime.h>
#include <hip/hip_bf16.h>

// B=4, T=2048, C=1024, H=16, Dh=64, M = B*T = 8192

typedef float f32x4 __attribute__((ext_vector_type(4)));
typedef __bf16 bf16x8 __attribute__((ext_vector_type(8)));

#define DEVI __device__ __forceinline__

// 0.125 (1/sqrt(Dh)) * log2(e): Q pre-scaled so softmax runs in base-2.
#define QSCALE 0.1803368801111204f

template<int N> struct IC { static constexpr int value = N; };

DEVI ushort f2b(float x) {
  __hip_bfloat16 h = __float2bfloat16(x);
  return __builtin_bit_cast(ushort, h);
}

DEVI unsigned int pkbf(float a, float b) {
#if __has_builtin(__builtin_amdgcn_cvt_pk_bf16_f32)
  typedef __bf16 bf16x2 __attribute__((ext_vector_type(2)));
  bf16x2 r = __builtin_amdgcn_cvt_pk_bf16_f32(a, b);
  return __builtin_bit_cast(unsigned int, r);
#else
  return (unsigned int)f2b(a) | ((unsigned int)f2b(b) << 16);
#endif
}

DEVI bf16x8 ldsFrag(const ushort* p) {
  return __builtin_bit_cast(bf16x8, *(const uint4*)p);
}

DEVI f32x4 mfma16(bf16x8 a, bf16x8 b, f32x4 c) {
  return __builtin_amdgcn_mfma_f32_16x16x32_bf16(a, b, c, 0, 0, 0);
}

DEVI void gload_lds16(const ushort* g, ushort* l) {
  __builtin_amdgcn_global_load_lds(
      (const __attribute__((address_space(1))) unsigned int*)g,
      (__attribute__((address_space(3))) unsigned int*)l, 16, 0, 0);
}

// raw barrier with scheduler pin on both sides
#define SBAR() do { __builtin_amdgcn_sched_barrier(0); \
                    __builtin_amdgcn_s_barrier();      \
                    __builtin_amdgcn_sched_barrier(0); } while (0)

// ---------------- fused fp32 -> bf16 convert (x + 4 weights) ----------------
__global__ void k_cvtAll(const float4* __restrict__ x,
                         const float4* __restrict__ w0, const float4* __restrict__ w1,
                         const float4* __restrict__ w2, const float4* __restrict__ w3,
                         ushort4* __restrict__ xb, ushort4* __restrict__ wcat) {
  const int blk = blockIdx.x;
  const int i = blk * 256 + threadIdx.x;
  float4 f;
  ushort4* dst;
  int di;
  if (blk < 8192) {                 // x: 2M float4
    f = x[i]; dst = xb; di = i;
  } else {                          // weights: 1M float4, 262144 per matrix
    const int wi = i - 8192 * 256;
    const int sel = wi >> 18;       // block-uniform (1024 blocks per W)
    const float4* src = (sel == 0) ? w0 : (sel == 1) ? w1 : (sel == 2) ? w2 : w3;
    f = src[wi & 262143]; dst = wcat; di = wi;
  }
  ushort4 o;
  o.x = f2b(f.x); o.y = f2b(f.y); o.z = f2b(f.z); o.w = f2b(f.w);
  dst[di] = o;
}

// ---------------- GEMM: out = A[M,K] * W[N,K]^T + bias ----------------
// R12: m201-geometry port. BM=BN=256, BK=32, 512 threads (8 waves, 2M x 4N)
// -> per-wave output 128x64 (the 62%-MfmaUtil aspect ratio).
// TRIPLE-buffered K-tiles (3 x 32 KB = 96 KB LDS; stage target never aliases
// the tile being read -> race-safe). Per K-tile: 2 phases (m-half), each
// {ds_reads + 2 gload_lds -> barrier -> setprio + 16 MFMA -> barrier}.
// B-frags read once per K-tile, held in regs (12 reads : 32 MFMA).
// Counted vmcnt(4) once per K-tile boundary; never drains in main loop.
// 4-chunk XOR swizzle for 32-elem rows (free 2-way on ds_read_b128).
// MODE 0: fused QKV (N=3072, 384 blocks); MODE 1: out-proj fp32 (128 blocks).
// Q/K and MODE1 use swapped-operand MFMA (computes C^T) for vectorized stores.
template<int MODE>
__global__ __launch_bounds__(512, 2)
void k_gemm(const ushort* __restrict__ A, const ushort* __restrict__ W,
            const float* __restrict__ b0, const float* __restrict__ b1,
            const float* __restrict__ b2, float* __restrict__ outF,
            ushort* __restrict__ oQ, ushort* __restrict__ oK, ushort* __restrict__ oV) {
  __shared__ ushort As[3][256 * 32];   // 48 KB
  __shared__ ushort Bs[3][256 * 32];   // 48 KB
  const int tid = threadIdx.x;
  const int wave = tid >> 6, lane = tid & 63;
  const int col = lane & 15, quad = lane >> 4;
  constexpr int NTI = (MODE == 0) ? 12 : 4;   // n-tiles
  constexpr int PER = NTI * 4;                // blocks per XCD
  const int id = blockIdx.x;
  const int L = (id & 7) * PER + (id >> 3);   // XCD-chunked, bijective
  const int m0 = (L & 31) * 256;
  const int n0 = (L >> 5) * 256;
  const int wm = (wave >> 2) * 128, wn = (wave & 3) * 64;

  // staging: wave stages rows [wave*32, +32) of A and of B per K-tile.
  // unit = 16 rows (64 lanes x 16 B); lane -> row lane>>2, chunk (lane&3)
  // pre-swizzled by ((lane>>3)&3) so ds_read_b128 is conflict-free.
  const int riu = lane >> 2;
  const int gch = ((lane & 3) ^ ((lane >> 3) & 3)) * 8;
  const ushort* Ag = A + (size_t)(m0 + wave * 32 + riu) * 1024 + gch;
  const ushort* Wg = W + (size_t)(n0 + wave * 32 + riu) * 1024 + gch;

  const int matId = (MODE == 0) ? (n0 >> 10) : 0;
  const int ko = (quad ^ ((col >> 1) & 3)) * 8;   // read-side swizzled k-chunk

  f32x4 acc[8][4] = {};
  bf16x8 bfr[4];

  auto stageA = [&](int t2, int buf) {
    const int ks = t2 * 32;
    gload_lds16(Ag + ks,             &As[buf][(wave * 32) * 32]);
    gload_lds16(Ag + 16 * 1024 + ks, &As[buf][(wave * 32 + 16) * 32]);
  };
  auto stageB = [&](int t2, int buf) {
    const int ks = t2 * 32;
    gload_lds16(Wg + ks,             &Bs[buf][(wave * 32) * 32]);
    gload_lds16(Wg + 16 * 1024 + ks, &Bs[buf][(wave * 32 + 16) * 32]);
  };

  auto kloop = [&](auto swc) {
    constexpr bool SW = (decltype(swc)::value != 0);
    // prologue: stage tiles 0,1 (8 loads); wait tile 0 (tile 1 in flight)
    stageA(0, 0); stageB(0, 0);
    stageA(1, 1); stageB(1, 1);
    asm volatile("s_waitcnt vmcnt(4)" ::: "memory");
    SBAR();
    int r0 = 0, r1 = 1, r2 = 2;               // r0 = buf of tile t
    for (int t = 0; t < 32; ++t) {
      const bool st = (t < 30);
      // ---- phase 0: m-half 0, B-frags for whole K-tile ----
      {
        bf16x8 af[4];
#pragma unroll
        for (int i = 0; i < 4; ++i)
          af[i] = ldsFrag(&As[r0][(wm + i * 16 + col) * 32 + ko]);
#pragma unroll
        for (int j = 0; j < 4; ++j)
          bfr[j] = ldsFrag(&Bs[r0][(wn + j * 16 + col) * 32 + ko]);
        if (st) stageA(t + 2, r2);
        SBAR();
        __builtin_amdgcn_s_setprio(1);
#pragma unroll
        for (int i = 0; i < 4; ++i)
#pragma unroll
          for (int j = 0; j < 4; ++j) {
            if constexpr (SW)
              acc[i][j] = mfma16(bfr[j], af[i], acc[i][j]);   // D = C^T tile
            else
              acc[i][j] = mfma16(af[i], bfr[j], acc[i][j]);
          }
        __builtin_amdgcn_s_setprio(0);
        SBAR();
      }
      // ---- phase 1: m-half 1, reuse bfr ----
      {
        bf16x8 af[4];
#pragma unroll
        for (int i = 0; i < 4; ++i)
          af[i] = ldsFrag(&As[r0][(wm + 64 + i * 16 + col) * 32 + ko]);
        if (st) stageB(t + 2, r2);
        SBAR();
        __builtin_amdgcn_s_setprio(1);
#pragma unroll
        for (int i = 0; i < 4; ++i)
#pragma unroll
          for (int j = 0; j < 4; ++j) {
            if constexpr (SW)
              acc[4 + i][j] = mfma16(bfr[j], af[i], acc[4 + i][j]);
            else
              acc[4 + i][j] = mfma16(af[i], bfr[j], acc[4 + i][j]);
          }
        __builtin_amdgcn_s_setprio(0);
        // tile t+1 must have landed; keep tile t+2's 4 loads in flight
        if (t < 30)       { asm volatile("s_waitcnt vmcnt(4)" ::: "memory"); }
        else if (t == 30) { asm volatile("s_waitcnt vmcnt(0)" ::: "memory"); }
        SBAR();
      }
      const int tmp = r0; r0 = r1; r1 = r2; r2 = tmp;
    }
  };

  if (MODE == 1 || matId < 2) kloop(IC<1>{}); else kloop(IC<0>{});

  if (MODE == 1) {
    // swapped: lane holds n = n0+wn+j*16+quad*4+r, m = m0+wm+h*64+i*16+col
#pragma unroll
    for (int h = 0; h < 2; ++h)
#pragma unroll
      for (int j = 0; j < 4; ++j) {
        const int nb = n0 + wn + j * 16 + quad * 4;
        const float4 bb = *(const float4*)&b0[nb];
#pragma unroll
        for (int i = 0; i < 4; ++i) {
          const int m = m0 + wm + h * 64 + i * 16 + col;
          float4 v;
          v.x = acc[h * 4 + i][j][0] + bb.x;
          v.y = acc[h * 4 + i][j][1] + bb.y;
          v.z = acc[h * 4 + i][j][2] + bb.z;
          v.w = acc[h * 4 + i][j][3] + bb.w;
          *(float4*)&outF[(size_t)m * 1024 + nb] = v;
        }
      }
  } else if (matId < 2) {
    // swapped: lane holds 4 consecutive dh at fixed t -> 8B stores
    ushort* dst = (matId == 0) ? oQ : oK;
    const float* bias = (matId == 0) ? b0 : b1;
    const float sc = (matId == 0) ? QSCALE : 1.0f;
#pragma unroll
    for (int h = 0; h < 2; ++h)
#pragma unroll
      for (int j = 0; j < 4; ++j) {
        const int nl = (n0 & 1023) + wn + j * 16 + quad * 4;
        const int hh = nl >> 6, dh0 = nl & 63;
        const float4 bb = *(const float4*)&bias[nl];
#pragma unroll
        for (int i = 0; i < 4; ++i) {
          const int m = m0 + wm + h * 64 + i * 16 + col;
          const int b = m >> 11, t = m & 2047;
          ushort4 pk;
          pk.x = f2b((acc[h * 4 + i][j][0] + bb.x) * sc);
          pk.y = f2b((acc[h * 4 + i][j][1] + bb.y) * sc);
          pk.z = f2b((acc[h * 4 + i][j][2] + bb.z) * sc);
          pk.w = f2b((acc[h * 4 + i][j][3] + bb.w) * sc);
          *(ushort4*)&dst[(((size_t)(b * 16 + hh) * 2048) + t) * 64 + dh0] = pk;
        }
      }
  } else {
    // V transposed [B,H,Dh,T]: unswapped, 4 consecutive t per r
#pragma unroll
    for (int h = 0; h < 2; ++h)
#pragma unroll
      for (int j = 0; j < 4; ++j) {
        const int nl = (n0 & 1023) + wn + j * 16 + col;
        const int hh = nl >> 6, dh = nl & 63;
        const float bn = b2[nl];
#pragma unroll
        for (int i = 0; i < 4; ++i) {
          const int mBase = m0 + wm + h * 64 + i * 16 + quad * 4;
          const int b = mBase >> 11, t = mBase & 2047;
          ushort4 pk;
          pk.x = f2b(acc[h * 4 + i][j][0] + bn);
          pk.y = f2b(acc[h * 4 + i][j][1] + bn);
          pk.z = f2b(acc[h * 4 + i][j][2] + bn);
          pk.w = f2b(acc[h * 4 + i][j][3] + bn);
          *(ushort4*)&oV[(((size_t)(b * 16 + hh) * 64) + dh) * 2048 + t] = pk;
        }
      }
  }
}

// ---------------- Flash attention (causal, base-2, no-max softmax) ----------------
// Q (pre-scaled), K: [BH,T,64]; Vt: [BH,64,T]; AO: [M,1024] bf16.
// One 256-q-row tile per block. Grid 512, LDS 69 KB, 2 blocks/CU.
// Block pairing: ids (x, x+256) get t + t' = 7 (balanced per-CU work).
__global__ __launch_bounds__(512, 4)
void k_attn(const ushort* __restrict__ Q, const ushort* __restrict__ K,
            const ushort* __restrict__ Vt, ushort* __restrict__ AO) {
  __shared__ ushort Ks[2 * 4096];          // [buf][kv 64][dh 64]
  __shared__ ushort Vs[2 * 4096];          // [buf][dh 64][kv 64]
  __shared__ ushort Os[512];               // ones A-tile: row0 = 1.0, rest 0
  __shared__ ushort Ps[16 * 16 * 72];      // [strip 16][q 16][kv 64 + pad]
  const int tid = threadIdx.x;
  const int wave = tid >> 6, lane = tid & 63;
  const int col = lane & 15, quad = lane >> 4;
  const int id = blockIdx.x;
  const int bh = (id & 7) * 8 + ((id >> 3) & 7);
  const int g = id >> 6;                   // 0..7
  const int t = (id < 256) ? (7 - g) : (g - 4);   // q-tile index 0..7
  const int q0 = t * 256;
  const ushort* Qg = Q + (size_t)bh * 2048 * 64;
  const ushort* Kg = K + (size_t)bh * 2048 * 64;
  const ushort* Vg = Vt + (size_t)bh * 64 * 2048;

  // init ones tile (A-operand: row0 = 1.0 across all k)
  if (tid < 128) {
    const ushort one = 0x3F80;
    ushort4 zv;
    if (tid < 8) { zv.x = one; zv.y = one; zv.z = one; zv.w = one; }
    else         { zv.x = 0;   zv.y = 0;   zv.z = 0;   zv.w = 0;   }
    *(ushort4*)&Os[tid * 4] = zv;
  }

  const int grow = lane >> 3;
  const int gchunk = ((lane & 7) ^ grow) * 8;
  const int cswz = col & 7;
  ushort* Pw0 = &Ps[((wave * 2 + 0) * 16 + col) * 72];
  ushort* Pw1 = &Ps[((wave * 2 + 1) * 16 + col) * 72];

  // Q B-frags for this wave's two strips
  bf16x8 qf[2][2];
#pragma unroll
  for (int s = 0; s < 2; ++s) {
    const ushort* p = Qg + (q0 + wave * 32 + s * 16 + col) * 64 + quad * 8;
    qf[s][0] = __builtin_bit_cast(bf16x8, *(const uint4*)p);
    qf[s][1] = __builtin_bit_cast(bf16x8, *(const uint4*)(p + 32));
  }

  f32x4 o[2][4] = {};
  f32x4 la[2] = {};

  const ushort* kPtr = Kg + (wave * 8 + grow) * 64 + gchunk;
  const ushort* vPtr = Vg + (size_t)(wave * 8 + grow) * 2048 + gchunk;

  auto stage = [&](auto bufc) {
    constexpr int BUF = decltype(bufc)::value;
    gload_lds16(kPtr, &Ks[BUF * 4096 + wave * 512]);
    gload_lds16(vPtr, &Vs[BUF * 4096 + wave * 512]);
    kPtr += 64 * 64;
    vPtr += 64;
  };

  auto step = [&](auto bufc, auto maskc, int j0) {
    constexpr int BUF = decltype(bufc)::value;
    constexpr bool MASKED = (decltype(maskc)::value != 0);
    const ushort* Kb = &Ks[BUF * 4096];
    const ushort* Vb = &Vs[BUF * 4096];
    bf16x8 kf[4][2];
#pragma unroll
    for (int i = 0; i < 4; ++i) {
      kf[i][0] = ldsFrag(&Kb[(i * 16 + col) * 64 + (((0 * 4 + quad) ^ cswz) * 8)]);
      kf[i][1] = ldsFrag(&Kb[(i * 16 + col) * 64 + (((1 * 4 + quad) ^ cswz) * 8)]);
    }
#pragma unroll
    for (int s = 0; s < 2; ++s) {
      ushort* Pw = s ? Pw1 : Pw0;
      const int dlim = MASKED ? (q0 + wave * 32 + s * 16 + col - j0 - quad * 4) : 0;
#pragma unroll
      for (int i = 0; i < 4; ++i) {
        f32x4 z = {0.f, 0.f, 0.f, 0.f};
        f32x4 sv = mfma16(kf[i][0], qf[s][0], z);
        sv = mfma16(kf[i][1], qf[s][1], sv);
        if (MASKED) {
#pragma unroll
          for (int r = 0; r < 4; ++r)
            if (i * 16 + r > dlim) sv[r] = -1e30f;
        }
        f32x4 pv;
#pragma unroll
        for (int r = 0; r < 4; ++r) pv[r] = __builtin_amdgcn_exp2f(sv[r]);
        uint2 pk;
        pk.x = pkbf(pv[0], pv[1]);
        pk.y = pkbf(pv[2], pv[3]);
        *(uint2*)&Pw[i * 16 + quad * 4] = pk;
      }
    }
    // PV: O^T[dh][q] += Vt * P^T ; l via ones-row MFMA
    bf16x8 osf = ldsFrag(&Os[col * 32 + quad * 8]);
#pragma unroll
    for (int c = 0; c < 2; ++c) {
      bf16x8 pb0 = ldsFrag(&Pw0[c * 32 + quad * 8]);
      bf16x8 pb1 = ldsFrag(&Pw1[c * 32 + quad * 8]);
      la[0] = mfma16(osf, pb0, la[0]);
      la[1] = mfma16(osf, pb1, la[1]);
#pragma unroll
      for (int i = 0; i < 4; ++i) {
        bf16x8 vf = ldsFrag(&Vb[(i * 16 + col) * 64 + (((c * 4 + quad) ^ cswz) * 8)]);
        o[0][i] = mfma16(vf, pb0, o[0][i]);
        o[1][i] = mfma16(vf, pb1, o[1][i]);
      }
    }
  };

  __syncthreads();                 // Os init visible
  stage(IC<0>{});                  // kv tile 0
  for (int it2 = 0; it2 < 2 * t; ++it2) {   // 4t full tiles
    __syncthreads();
    stage(IC<1>{});
    step(IC<0>{}, IC<0>{}, 0);
    __syncthreads();
    stage(IC<0>{});
    step(IC<1>{}, IC<0>{}, 0);
  }
  // 4 diagonal tiles (kv = q0 .. q0+256), parities 0,1,0,1
  __syncthreads();
  stage(IC<1>{});
  step(IC<0>{}, IC<1>{}, q0);
  __syncthreads();
  stage(IC<0>{});
  if (wave >= 2) step(IC<1>{}, IC<1>{}, q0 + 64);
  __syncthreads();
  stage(IC<1>{});
  if (wave >= 4) step(IC<0>{}, IC<1>{}, q0 + 128);
  __syncthreads();
  if (wave >= 6) step(IC<1>{}, IC<1>{}, q0 + 192);

  // epilogue: O^T C-layout: row dh = i*16 + quad*4 + r, col q = col
  const float invs[2] = {1.0f / __shfl(la[0][0], col), 1.0f / __shfl(la[1][0], col)};
  const int b = bh >> 4, h = bh & 15;
#pragma unroll
  for (int s = 0; s < 2; ++s) {
    const float inv = invs[s];
    const int tq = q0 + wave * 32 + s * 16 + col;
    ushort* dst = AO + (size_t)(b * 2048 + tq) * 1024 + h * 64;
#pragma unroll
    for (int i = 0; i < 4; ++i) {
      f32x4 v = o[s][i];
      ushort4 pk;
      pk.x = f2b(v[0] * inv);
      pk.y = f2b(v[1] * inv);
      pk.z = f2b(v[2] * inv);
      pk.w = f2b(v[3] * inv);
      *(ushort4*)&dst[i * 16 + quad * 4] = pk;
    }
  }
}

// ---------------- launch ----------------
extern "C" void kernel_launch(void* const* d_in, const int* in_sizes, int n_in,
                              void* d_out, int out_size, void* d_ws, size_t ws_size,
                              hipStream_t stream) {
  const float* x  = (const float*)d_in[0];
  const float* Wq = (const float*)d_in[1];
  const float* bq = (const float*)d_in[2];
  const float* Wk = (const float*)d_in[3];
  const float* bk = (const float*)d_in[4];
  const float* Wv = (const float*)d_in[5];
  const float* bv = (const float*)d_in[6];
  const float* Wo = (const float*)d_in[7];
  const float* bo = (const float*)d_in[8];
  float* out = (float*)d_out;

  char* ws = (char*)d_ws;
  ushort* xb    = (ushort*)ws;                                 // 16 MB
  ushort* Wcat  = (ushort*)(ws + (size_t)16 * 1024 * 1024);    // 8 MB (Wq|Wk|Wv|Wo)
  ushort* Wob   = Wcat + (size_t)3 * 1024 * 1024;
  ushort* Qh    = (ushort*)(ws + (size_t)24 * 1024 * 1024);    // 16 MB
  ushort* Kh    = Qh + (size_t)8192 * 1024;
  ushort* Vt    = Kh + (size_t)8192 * 1024;
  ushort* AO    = Vt + (size_t)8192 * 1024;

  // fused converts: x (8192 blocks) + 4 weights (4096 blocks)
  k_cvtAll<<<12288, 256, 0, stream>>>((const float4*)x,
                                      (const float4*)Wq, (const float4*)Wk,
                                      (const float4*)Wv, (const float4*)Wo,
                                      (ushort4*)xb, (ushort4*)Wcat);

  // fused QKV GEMM: N = 3072, 32 x 12 = 384 blocks (256^2 tiles)
  k_gemm<0><<<384, 512, 0, stream>>>(xb, Wcat, bq, bk, bv, nullptr, Qh, Kh, Vt);

  // attention: 512 blocks (bh x q-tile), 2 blocks/CU
  k_attn<<<512, 512, 0, stream>>>(Qh, Kh, Vt, AO);

  // out-projection: N = 1024, 32 x 4 = 128 blocks, fp32 out
  k_gemm<1><<<128, 512, 0, stream>>>(AO, Wob, bo, nullptr, nullptr, out,
                                     nullptr, nullptr, nullptr);
}

// Round 5
// 254.827 us; speedup vs baseline: 1.0847x; 1.0847x over previous
//
#include <hip/hip_runtime.h>
#include <hip/hip_bf16.h>

// B=4, T=2048, C=1024, H=16, Dh=64, M = B*T = 8192

typedef float f32x4 __attribute__((ext_vector_type(4)));
typedef __bf16 bf16x8 __attribute__((ext_vector_type(8)));

#define DEVI __device__ __forceinline__

// 0.125 (1/sqrt(Dh)) * log2(e): Q pre-scaled so softmax runs in base-2.
#define QSCALE 0.1803368801111204f

template<int N> struct IC { static constexpr int value = N; };

DEVI ushort f2b(float x) {
  __hip_bfloat16 h = __float2bfloat16(x);
  return __builtin_bit_cast(ushort, h);
}

DEVI unsigned int pkbf(float a, float b) {
#if __has_builtin(__builtin_amdgcn_cvt_pk_bf16_f32)
  typedef __bf16 bf16x2 __attribute__((ext_vector_type(2)));
  bf16x2 r = __builtin_amdgcn_cvt_pk_bf16_f32(a, b);
  return __builtin_bit_cast(unsigned int, r);
#else
  return (unsigned int)f2b(a) | ((unsigned int)f2b(b) << 16);
#endif
}

DEVI bf16x8 ldsFrag(const ushort* p) {
  return __builtin_bit_cast(bf16x8, *(const uint4*)p);
}

DEVI f32x4 mfma16(bf16x8 a, bf16x8 b, f32x4 c) {
  return __builtin_amdgcn_mfma_f32_16x16x32_bf16(a, b, c, 0, 0, 0);
}

DEVI void gload_lds16(const ushort* g, ushort* l) {
  __builtin_amdgcn_global_load_lds(
      (const __attribute__((address_space(1))) unsigned int*)g,
      (__attribute__((address_space(3))) unsigned int*)l, 16, 0, 0);
}

// raw barrier with scheduler pin on both sides
#define SBAR() do { __builtin_amdgcn_sched_barrier(0); \
                    __builtin_amdgcn_s_barrier();      \
                    __builtin_amdgcn_sched_barrier(0); } while (0)

// ---------------- fused fp32 -> bf16 convert (x + 4 weights) ----------------
__global__ void k_cvtAll(const float4* __restrict__ x,
                         const float4* __restrict__ w0, const float4* __restrict__ w1,
                         const float4* __restrict__ w2, const float4* __restrict__ w3,
                         ushort4* __restrict__ xb, ushort4* __restrict__ wcat) {
  const int blk = blockIdx.x;
  const int i = blk * 256 + threadIdx.x;
  float4 f;
  ushort4* dst;
  int di;
  if (blk < 8192) {                 // x: 2M float4
    f = x[i]; dst = xb; di = i;
  } else {                          // weights: 1M float4, 262144 per matrix
    const int wi = i - 8192 * 256;
    const int sel = wi >> 18;       // block-uniform (1024 blocks per W)
    const float4* src = (sel == 0) ? w0 : (sel == 1) ? w1 : (sel == 2) ? w2 : w3;
    f = src[wi & 262143]; dst = wcat; di = wi;
  }
  ushort4 o;
  o.x = f2b(f.x); o.y = f2b(f.y); o.z = f2b(f.z); o.w = f2b(f.w);
  dst[di] = o;
}

// ---------------- QKV GEMM: 256x256 tile, BK=64, m201-style 4-phase ----------------
// 512 threads, 8 waves as 2M x 4N -> per-wave output 128x64 (0.375 ds_reads
// per MFMA). Double-buffered LDS 128 KB. Per K-tile: 4 phases (kk-major:
// (k0,h0),(k0,h1),(k1,h0),(k1,h1)), each {4-8 ds_read_b128 [+ staging] ->
// barrier -> lgkmcnt(0) -> setprio + 16 MFMA -> barrier}. B-frags read once
// per kk, reused across m-halves. Staging of tile t+1 (8 gload_lds units of
// 8 rows x 128 B, R1's proven swizzle) front-loaded into phases 0-1; single
// vmcnt(0) at tile boundary lands ~2 phases after last issue. Stage buffer
// never aliases the read buffer -> race-free.
// N=3072: n-tiles 0-7 = Q/K (swapped MFMA, C^T), 8-11 = V (unswapped,
// transposed store). Grid 384 = 32 m x 12 n, XCD-chunked.
__global__ __launch_bounds__(512, 2)
void k_gemm256(const ushort* __restrict__ A, const ushort* __restrict__ W,
               const float* __restrict__ b0, const float* __restrict__ b1,
               const float* __restrict__ b2,
               ushort* __restrict__ oQ, ushort* __restrict__ oK,
               ushort* __restrict__ oV) {
  __shared__ ushort As[2][256 * 64];   // 64 KB
  __shared__ ushort Bs[2][256 * 64];   // 64 KB
  const int tid = threadIdx.x;
  const int wave = tid >> 6, lane = tid & 63;
  const int col = lane & 15, quad = lane >> 4;
  const int id = blockIdx.x;
  const int L = (id & 7) * 48 + (id >> 3);   // XCD-chunked, bijective (384=8*48)
  const int m0 = (L & 31) * 256;
  const int n0 = (L >> 5) * 256;
  const int wm = (wave >> 2) * 128, wn = (wave & 3) * 64;
  const int matId = n0 >> 10;                 // 0=Q 1=K 2=V

  // staging: R1's proven unit = 8 rows x 128 B, global chunk pre-XOR'd by row
  const int grow = lane >> 3;                 // 0..7
  const int gchunk = ((lane & 7) ^ grow) * 8; // swizzled k-offset (elements)
  const int cswz = col & 7;
  const ushort* Ag = A + (size_t)(m0 + wave * 32 + grow) * 1024 + gchunk;
  const ushort* Wg = W + (size_t)(n0 + wave * 32 + grow) * 1024 + gchunk;

  f32x4 acc[8][4] = {};
  bf16x8 bfr[4];

  // stage half hf (units 2hf, 2hf+1 of both A and B) of tile t1
  auto stageHalf = [&](int t1, int hf) {
    const int buf = t1 & 1;
    const int ks = t1 * 64;
#pragma unroll
    for (int u = 2 * hf; u < 2 * hf + 2; ++u) {
      gload_lds16(Ag + (size_t)u * 8 * 1024 + ks, &As[buf][(wave * 32 + u * 8) * 64]);
      gload_lds16(Wg + (size_t)u * 8 * 1024 + ks, &Bs[buf][(wave * 32 + u * 8) * 64]);
    }
  };

  auto kloop = [&](auto swc) {
    constexpr bool SW = (decltype(swc)::value != 0);
    // MFMA cluster for (h, kk): af read fresh each phase, bfr reused per kk
    auto phase = [&](int p, int h, int kk, bool rdB, auto stg) {
      const int ko = ((kk * 4 + quad) ^ cswz) * 8;
      bf16x8 af[4];
#pragma unroll
      for (int i = 0; i < 4; ++i)
        af[i] = ldsFrag(&As[p][(wm + h * 64 + i * 16 + col) * 64 + ko]);
      if (rdB) {
#pragma unroll
        for (int j = 0; j < 4; ++j)
          bfr[j] = ldsFrag(&Bs[p][(wn + j * 16 + col) * 64 + ko]);
      }
      stg();
      SBAR();
      asm volatile("s_waitcnt lgkmcnt(0)" ::: "memory");
      __builtin_amdgcn_sched_barrier(0);
      __builtin_amdgcn_s_setprio(1);
#pragma unroll
      for (int i = 0; i < 4; ++i)
#pragma unroll
        for (int j = 0; j < 4; ++j) {
          if constexpr (SW)
            acc[h * 4 + i][j] = mfma16(bfr[j], af[i], acc[h * 4 + i][j]);
          else
            acc[h * 4 + i][j] = mfma16(af[i], bfr[j], acc[h * 4 + i][j]);
        }
      __builtin_amdgcn_s_setprio(0);
      SBAR();
    };

    // prologue: stage tile 0, drain, barrier
    stageHalf(0, 0); stageHalf(0, 1);
    asm volatile("s_waitcnt vmcnt(0)" ::: "memory");
    SBAR();

    for (int t = 0; t < 16; ++t) {
      const int p = t & 1;
      const bool st = (t < 15);
      phase(p, 0, 0, true,  [&] { if (st) stageHalf(t + 1, 0); });
      phase(p, 1, 0, false, [&] { if (st) stageHalf(t + 1, 1); });
      phase(p, 0, 1, true,  [&] {});
      // last phase: fold boundary wait in before its trailing barrier
      {
        const int ko = ((1 * 4 + quad) ^ cswz) * 8;
        bf16x8 af[4];
#pragma unroll
        for (int i = 0; i < 4; ++i)
          af[i] = ldsFrag(&As[p][(wm + 64 + i * 16 + col) * 64 + ko]);
        SBAR();
        asm volatile("s_waitcnt lgkmcnt(0)" ::: "memory");
        __builtin_amdgcn_sched_barrier(0);
        __builtin_amdgcn_s_setprio(1);
#pragma unroll
        for (int i = 0; i < 4; ++i)
#pragma unroll
          for (int j = 0; j < 4; ++j) {
            if constexpr (SW)
              acc[4 + i][j] = mfma16(bfr[j], af[i], acc[4 + i][j]);
            else
              acc[4 + i][j] = mfma16(af[i], bfr[j], acc[4 + i][j]);
          }
        __builtin_amdgcn_s_setprio(0);
        if (st) { asm volatile("s_waitcnt vmcnt(0)" ::: "memory"); }
        SBAR();
      }
    }
  };

  if (matId < 2) kloop(IC<1>{}); else kloop(IC<0>{});

  if (matId < 2) {
    // swapped: lane holds 4 consecutive dh at fixed t -> 8B stores
    ushort* dst = (matId == 0) ? oQ : oK;
    const float* bias = (matId == 0) ? b0 : b1;
    const float sc = (matId == 0) ? QSCALE : 1.0f;
#pragma unroll
    for (int h = 0; h < 2; ++h)
#pragma unroll
      for (int j = 0; j < 4; ++j) {
        const int nl = (n0 & 1023) + wn + j * 16 + quad * 4;
        const int hh = nl >> 6, dh0 = nl & 63;
        const float4 bb = *(const float4*)&bias[nl];
#pragma unroll
        for (int i = 0; i < 4; ++i) {
          const int m = m0 + wm + h * 64 + i * 16 + col;
          const int b = m >> 11, t = m & 2047;
          ushort4 pk;
          pk.x = f2b((acc[h * 4 + i][j][0] + bb.x) * sc);
          pk.y = f2b((acc[h * 4 + i][j][1] + bb.y) * sc);
          pk.z = f2b((acc[h * 4 + i][j][2] + bb.z) * sc);
          pk.w = f2b((acc[h * 4 + i][j][3] + bb.w) * sc);
          *(ushort4*)&dst[(((size_t)(b * 16 + hh) * 2048) + t) * 64 + dh0] = pk;
        }
      }
  } else {
    // V transposed [B,H,Dh,T]: unswapped, 4 consecutive t per r
#pragma unroll
    for (int h = 0; h < 2; ++h)
#pragma unroll
      for (int j = 0; j < 4; ++j) {
        const int nl = (n0 & 1023) + wn + j * 16 + col;
        const int hh = nl >> 6, dh = nl & 63;
        const float bn = b2[nl];
#pragma unroll
        for (int i = 0; i < 4; ++i) {
          const int mBase = m0 + wm + h * 64 + i * 16 + quad * 4;
          const int b = mBase >> 11, t = mBase & 2047;
          ushort4 pk;
          pk.x = f2b(acc[h * 4 + i][j][0] + bn);
          pk.y = f2b(acc[h * 4 + i][j][1] + bn);
          pk.z = f2b(acc[h * 4 + i][j][2] + bn);
          pk.w = f2b(acc[h * 4 + i][j][3] + bn);
          *(ushort4*)&oV[(((size_t)(b * 16 + hh) * 64) + dh) * 2048 + t] = pk;
        }
      }
  }
}

// ---------------- out-proj GEMM (R1-verified structure) ----------------
// 128x256 tile, BK=64, 512 threads (8 waves, 2M x 4N), TRIPLE-buffered LDS
// (144 KB), 2 phases per K-tile, counted vmcnt(6), setprio, XOR swizzle.
// Swapped-operand MFMA (computes C^T) for vectorized fp32 stores. 256 blocks.
__global__ __launch_bounds__(512, 2)
void k_gemmP(const ushort* __restrict__ A, const ushort* __restrict__ W,
             const float* __restrict__ b0, float* __restrict__ outF) {
  __shared__ ushort As[3 * 128 * 64];   // 48 KB, tile t in buf t%3
  __shared__ ushort Bs[3 * 256 * 64];   // 96 KB
  const int tid = threadIdx.x;
  const int wave = tid >> 6, lane = tid & 63;
  const int col = lane & 15, quad = lane >> 4;
  const int id = blockIdx.x;
  const int s_ = id >> 3;
  const int m0 = ((id & 7) * 8 + (s_ & 7)) * 128;   // 64 m-tiles, 8 per XCD
  const int n0 = (s_ >> 3) * 256;
  const int wm = (wave >> 2) * 64, wn = (wave & 3) * 64;
  f32x4 acc[4][4] = {};

  const int grow = lane >> 3;                 // 0..7
  const int gchunk = ((lane & 7) ^ grow) * 8; // swizzled k-offset (elements)
  const int cswz = col & 7;
  const ushort* Ag = A + (size_t)(m0 + wave * 16 + grow) * 1024 + gchunk;
  const ushort* Wg = W + (size_t)(n0 + wave * 32 + grow) * 1024 + gchunk;
  ushort* AsW = &As[wave * 1024];
  ushort* BsW = &Bs[wave * 2048];

  auto stageA = [&](int ks, int sb) {
    gload_lds16(Ag + ks,        AsW + sb * 8192);
    gload_lds16(Ag + ks + 8192, AsW + sb * 8192 + 512);
  };
  auto stageBh = [&](int ks, int sb, int h) {   // h = 0/1: 16-row half of B stripe
    const ushort* sp = Wg + ks + h * 16384;
    ushort* dp = BsW + sb * 16384 + h * 1024;
    gload_lds16(sp,        dp);
    gload_lds16(sp + 8192, dp + 512);
  };

  auto phase = [&](int cur, int kk, auto stagef) {
    const int ko = ((kk * 4 + quad) ^ cswz) * 8;
    const ushort* Ab = &As[cur * 8192];
    const ushort* Bb = &Bs[cur * 16384];
    bf16x8 af[4], bfr[4];
#pragma unroll
    for (int i = 0; i < 4; ++i)
      af[i] = ldsFrag(&Ab[(wm + i * 16 + col) * 64 + ko]);
#pragma unroll
    for (int j = 0; j < 4; ++j)
      bfr[j] = ldsFrag(&Bb[(wn + j * 16 + col) * 64 + ko]);
    stagef();
    SBAR();
    __builtin_amdgcn_s_setprio(1);
#pragma unroll
    for (int i = 0; i < 4; ++i)
#pragma unroll
      for (int j = 0; j < 4; ++j)
        acc[i][j] = mfma16(bfr[j], af[i], acc[i][j]);   // D = C^T tile
    __builtin_amdgcn_s_setprio(0);
  };

  // prologue: stage tiles 0,1 (12 loads); wait tile0 (6 may stay in flight)
  stageA(0, 0);  stageBh(0, 0, 0);  stageBh(0, 0, 1);
  stageA(64, 1); stageBh(64, 1, 0); stageBh(64, 1, 1);
  asm volatile("s_waitcnt vmcnt(6)" ::: "memory");
  SBAR();

  int r0 = 0, r1 = 1, r2 = 2;                // r0 = buf of tile t
  for (int t = 0; t < 14; ++t) {
    const int ks = (t + 2) * 64;
    phase(r0, 0, [&] { stageA(ks, r2); stageBh(ks, r2, 0); });
    SBAR();
    phase(r0, 1, [&] { stageBh(ks, r2, 1); });
    asm volatile("s_waitcnt vmcnt(6)" ::: "memory");
    SBAR();
    const int tmp = r0; r0 = r1; r1 = r2; r2 = tmp;
  }
  phase(r0, 0, [&] {});
  SBAR();
  phase(r0, 1, [&] {});
  asm volatile("s_waitcnt vmcnt(0)" ::: "memory");
  SBAR();
  phase(r1, 0, [&] {});
  SBAR();
  phase(r1, 1, [&] {});

  // swapped: lane holds n = n0+wn+j*16+quad*4+r, m = m0+wm+i*16+col
#pragma unroll
  for (int j = 0; j < 4; ++j) {
    const int nb = n0 + wn + j * 16 + quad * 4;
    const float4 bb = *(const float4*)&b0[nb];
#pragma unroll
    for (int i = 0; i < 4; ++i) {
      const int m = m0 + wm + i * 16 + col;
      float4 v;
      v.x = acc[i][j][0] + bb.x;
      v.y = acc[i][j][1] + bb.y;
      v.z = acc[i][j][2] + bb.z;
      v.w = acc[i][j][3] + bb.w;
      *(float4*)&outF[(size_t)m * 1024 + nb] = v;
    }
  }
}

// ---------------- Flash attention (causal, base-2, no-max softmax) ----------------
// Q (pre-scaled), K: [BH,T,64]; Vt: [BH,64,T]; AO: [M,1024] bf16.
// One 256-q-row tile per block. Grid 512, LDS 69 KB, 2 blocks/CU.
// Block pairing: ids (x, x+256) get t + t' = 7 (balanced per-CU work).
__global__ __launch_bounds__(512, 4)
void k_attn(const ushort* __restrict__ Q, const ushort* __restrict__ K,
            const ushort* __restrict__ Vt, ushort* __restrict__ AO) {
  __shared__ ushort Ks[2 * 4096];          // [buf][kv 64][dh 64]
  __shared__ ushort Vs[2 * 4096];          // [buf][dh 64][kv 64]
  __shared__ ushort Os[512];               // ones A-tile: row0 = 1.0, rest 0
  __shared__ ushort Ps[16 * 16 * 72];      // [strip 16][q 16][kv 64 + pad]
  const int tid = threadIdx.x;
  const int wave = tid >> 6, lane = tid & 63;
  const int col = lane & 15, quad = lane >> 4;
  const int id = blockIdx.x;
  const int bh = (id & 7) * 8 + ((id >> 3) & 7);
  const int g = id >> 6;                   // 0..7
  const int t = (id < 256) ? (7 - g) : (g - 4);   // q-tile index 0..7
  const int q0 = t * 256;
  const ushort* Qg = Q + (size_t)bh * 2048 * 64;
  const ushort* Kg = K + (size_t)bh * 2048 * 64;
  const ushort* Vg = Vt + (size_t)bh * 64 * 2048;

  // init ones tile (A-operand: row0 = 1.0 across all k)
  if (tid < 128) {
    const ushort one = 0x3F80;
    ushort4 zv;
    if (tid < 8) { zv.x = one; zv.y = one; zv.z = one; zv.w = one; }
    else         { zv.x = 0;   zv.y = 0;   zv.z = 0;   zv.w = 0;   }
    *(ushort4*)&Os[tid * 4] = zv;
  }

  const int grow = lane >> 3;
  const int gchunk = ((lane & 7) ^ grow) * 8;
  const int cswz = col & 7;
  ushort* Pw0 = &Ps[((wave * 2 + 0) * 16 + col) * 72];
  ushort* Pw1 = &Ps[((wave * 2 + 1) * 16 + col) * 72];

  // Q B-frags for this wave's two strips
  bf16x8 qf[2][2];
#pragma unroll
  for (int s = 0; s < 2; ++s) {
    const ushort* p = Qg + (q0 + wave * 32 + s * 16 + col) * 64 + quad * 8;
    qf[s][0] = __builtin_bit_cast(bf16x8, *(const uint4*)p);
    qf[s][1] = __builtin_bit_cast(bf16x8, *(const uint4*)(p + 32));
  }

  f32x4 o[2][4] = {};
  f32x4 la[2] = {};

  const ushort* kPtr = Kg + (wave * 8 + grow) * 64 + gchunk;
  const ushort* vPtr = Vg + (size_t)(wave * 8 + grow) * 2048 + gchunk;

  auto stage = [&](auto bufc) {
    constexpr int BUF = decltype(bufc)::value;
    gload_lds16(kPtr, &Ks[BUF * 4096 + wave * 512]);
    gload_lds16(vPtr, &Vs[BUF * 4096 + wave * 512]);
    kPtr += 64 * 64;
    vPtr += 64;
  };

  auto step = [&](auto bufc, auto maskc, int j0) {
    constexpr int BUF = decltype(bufc)::value;
    constexpr bool MASKED = (decltype(maskc)::value != 0);
    const ushort* Kb = &Ks[BUF * 4096];
    const ushort* Vb = &Vs[BUF * 4096];
    bf16x8 kf[4][2];
#pragma unroll
    for (int i = 0; i < 4; ++i) {
      kf[i][0] = ldsFrag(&Kb[(i * 16 + col) * 64 + (((0 * 4 + quad) ^ cswz) * 8)]);
      kf[i][1] = ldsFrag(&Kb[(i * 16 + col) * 64 + (((1 * 4 + quad) ^ cswz) * 8)]);
    }
#pragma unroll
    for (int s = 0; s < 2; ++s) {
      ushort* Pw = s ? Pw1 : Pw0;
      const int dlim = MASKED ? (q0 + wave * 32 + s * 16 + col - j0 - quad * 4) : 0;
#pragma unroll
      for (int i = 0; i < 4; ++i) {
        f32x4 z = {0.f, 0.f, 0.f, 0.f};
        f32x4 sv = mfma16(kf[i][0], qf[s][0], z);
        sv = mfma16(kf[i][1], qf[s][1], sv);
        if (MASKED) {
#pragma unroll
          for (int r = 0; r < 4; ++r)
            if (i * 16 + r > dlim) sv[r] = -1e30f;
        }
        f32x4 pv;
#pragma unroll
        for (int r = 0; r < 4; ++r) pv[r] = __builtin_amdgcn_exp2f(sv[r]);
        uint2 pk;
        pk.x = pkbf(pv[0], pv[1]);
        pk.y = pkbf(pv[2], pv[3]);
        *(uint2*)&Pw[i * 16 + quad * 4] = pk;
      }
    }
    // PV: O^T[dh][q] += Vt * P^T ; l via ones-row MFMA
    bf16x8 osf = ldsFrag(&Os[col * 32 + quad * 8]);
#pragma unroll
    for (int c = 0; c < 2; ++c) {
      bf16x8 pb0 = ldsFrag(&Pw0[c * 32 + quad * 8]);
      bf16x8 pb1 = ldsFrag(&Pw1[c * 32 + quad * 8]);
      la[0] = mfma16(osf, pb0, la[0]);
      la[1] = mfma16(osf, pb1, la[1]);
#pragma unroll
      for (int i = 0; i < 4; ++i) {
        bf16x8 vf = ldsFrag(&Vb[(i * 16 + col) * 64 + (((c * 4 + quad) ^ cswz) * 8)]);
        o[0][i] = mfma16(vf, pb0, o[0][i]);
        o[1][i] = mfma16(vf, pb1, o[1][i]);
      }
    }
  };

  __syncthreads();                 // Os init visible
  stage(IC<0>{});                  // kv tile 0
  for (int it2 = 0; it2 < 2 * t; ++it2) {   // 4t full tiles
    __syncthreads();
    stage(IC<1>{});
    step(IC<0>{}, IC<0>{}, 0);
    __syncthreads();
    stage(IC<0>{});
    step(IC<1>{}, IC<0>{}, 0);
  }
  // 4 diagonal tiles (kv = q0 .. q0+256), parities 0,1,0,1
  __syncthreads();
  stage(IC<1>{});
  step(IC<0>{}, IC<1>{}, q0);
  __syncthreads();
  stage(IC<0>{});
  if (wave >= 2) step(IC<1>{}, IC<1>{}, q0 + 64);
  __syncthreads();
  stage(IC<1>{});
  if (wave >= 4) step(IC<0>{}, IC<1>{}, q0 + 128);
  __syncthreads();
  if (wave >= 6) step(IC<1>{}, IC<1>{}, q0 + 192);

  // epilogue: O^T C-layout: row dh = i*16 + quad*4 + r, col q = col
  const float invs[2] = {1.0f / __shfl(la[0][0], col), 1.0f / __shfl(la[1][0], col)};
  const int b = bh >> 4, h = bh & 15;
#pragma unroll
  for (int s = 0; s < 2; ++s) {
    const float inv = invs[s];
    const int tq = q0 + wave * 32 + s * 16 + col;
    ushort* dst = AO + (size_t)(b * 2048 + tq) * 1024 + h * 64;
#pragma unroll
    for (int i = 0; i < 4; ++i) {
      f32x4 v = o[s][i];
      ushort4 pk;
      pk.x = f2b(v[0] * inv);
      pk.y = f2b(v[1] * inv);
      pk.z = f2b(v[2] * inv);
      pk.w = f2b(v[3] * inv);
      *(ushort4*)&dst[i * 16 + quad * 4] = pk;
    }
  }
}

// ---------------- launch ----------------
extern "C" void kernel_launch(void* const* d_in, const int* in_sizes, int n_in,
                              void* d_out, int out_size, void* d_ws, size_t ws_size,
                              hipStream_t stream) {
  const float* x  = (const float*)d_in[0];
  const float* Wq = (const float*)d_in[1];
  const float* bq = (const float*)d_in[2];
  const float* Wk = (const float*)d_in[3];
  const float* bk = (const float*)d_in[4];
  const float* Wv = (const float*)d_in[5];
  const float* bv = (const float*)d_in[6];
  const float* Wo = (const float*)d_in[7];
  const float* bo = (const float*)d_in[8];
  float* out = (float*)d_out;

  char* ws = (char*)d_ws;
  ushort* xb    = (ushort*)ws;                                 // 16 MB
  ushort* Wcat  = (ushort*)(ws + (size_t)16 * 1024 * 1024);    // 8 MB (Wq|Wk|Wv|Wo)
  ushort* Wob   = Wcat + (size_t)3 * 1024 * 1024;
  ushort* Qh    = (ushort*)(ws + (size_t)24 * 1024 * 1024);    // 16 MB
  ushort* Kh    = Qh + (size_t)8192 * 1024;
  ushort* Vt    = Kh + (size_t)8192 * 1024;
  ushort* AO    = Vt + (size_t)8192 * 1024;

  // fused converts: x (8192 blocks) + 4 weights (4096 blocks)
  k_cvtAll<<<12288, 256, 0, stream>>>((const float4*)x,
                                      (const float4*)Wq, (const float4*)Wk,
                                      (const float4*)Wv, (const float4*)Wo,
                                      (ushort4*)xb, (ushort4*)Wcat);

  // fused QKV GEMM: N = 3072, 32 x 12 = 384 blocks (256^2 tiles, 4-phase)
  k_gemm256<<<384, 512, 0, stream>>>(xb, Wcat, bq, bk, bv, Qh, Kh, Vt);

  // attention: 512 blocks (bh x q-tile), 2 blocks/CU
  k_attn<<<512, 512, 0, stream>>>(Qh, Kh, Vt, AO);

  // out-projection: N = 1024, 256 blocks, fp32 out (R1-verified kernel)
  k_gemmP<<<256, 512, 0, stream>>>(AO, Wob, bo, out);
}

// Round 6
// 245.854 us; speedup vs baseline: 1.1243x; 1.0365x over previous
//
#include <hip/hip_runtime.h>
#include <hip/hip_bf16.h>

// B=4, T=2048, C=1024, H=16, Dh=64, M = B*T = 8192

typedef float f32x4 __attribute__((ext_vector_type(4)));
typedef __bf16 bf16x8 __attribute__((ext_vector_type(8)));

#define DEVI __device__ __forceinline__

// 0.125 (1/sqrt(Dh)) * log2(e): Q pre-scaled so softmax runs in base-2.
#define QSCALE 0.1803368801111204f

template<int N> struct IC { static constexpr int value = N; };

DEVI ushort f2b(float x) {
  __hip_bfloat16 h = __float2bfloat16(x);
  return __builtin_bit_cast(ushort, h);
}

DEVI unsigned int pkbf(float a, float b) {
#if __has_builtin(__builtin_amdgcn_cvt_pk_bf16_f32)
  typedef __bf16 bf16x2 __attribute__((ext_vector_type(2)));
  bf16x2 r = __builtin_amdgcn_cvt_pk_bf16_f32(a, b);
  return __builtin_bit_cast(unsigned int, r);
#else
  return (unsigned int)f2b(a) | ((unsigned int)f2b(b) << 16);
#endif
}

DEVI bf16x8 ldsFrag(const ushort* p) {
  return __builtin_bit_cast(bf16x8, *(const uint4*)p);
}

DEVI f32x4 mfma16(bf16x8 a, bf16x8 b, f32x4 c) {
  return __builtin_amdgcn_mfma_f32_16x16x32_bf16(a, b, c, 0, 0, 0);
}

DEVI void gload_lds16(const ushort* g, ushort* l) {
  __builtin_amdgcn_global_load_lds(
      (const __attribute__((address_space(1))) unsigned int*)g,
      (__attribute__((address_space(3))) unsigned int*)l, 16, 0, 0);
}

// raw barrier with scheduler pin on both sides
#define SBAR() do { __builtin_amdgcn_sched_barrier(0); \
                    __builtin_amdgcn_s_barrier();      \
                    __builtin_amdgcn_sched_barrier(0); } while (0)

// ---------------- fused fp32 -> bf16 convert (x + 4 weights) ----------------
__global__ void k_cvtAll(const float4* __restrict__ x,
                         const float4* __restrict__ w0, const float4* __restrict__ w1,
                         const float4* __restrict__ w2, const float4* __restrict__ w3,
                         ushort4* __restrict__ xb, ushort4* __restrict__ wcat) {
  const int blk = blockIdx.x;
  const int i = blk * 256 + threadIdx.x;
  float4 f;
  ushort4* dst;
  int di;
  if (blk < 8192) {                 // x: 2M float4
    f = x[i]; dst = xb; di = i;
  } else {                          // weights: 1M float4, 262144 per matrix
    const int wi = i - 8192 * 256;
    const int sel = wi >> 18;       // block-uniform (1024 blocks per W)
    const float4* src = (sel == 0) ? w0 : (sel == 1) ? w1 : (sel == 2) ? w2 : w3;
    f = src[wi & 262143]; dst = wcat; di = wi;
  }
  ushort4 o;
  o.x = f2b(f.x); o.y = f2b(f.y); o.z = f2b(f.z); o.w = f2b(f.w);
  dst[di] = o;
}

// ---------------- fused QKV GEMM: 256x384 tile, ONE perfect round ----------------
// R13: block computes a 256x256 QK tile (swapped MFMA, C^T) AND a 256x128 V
// tile (unswapped) sharing the same A-tile. Grid = 32 m x 8 n = 256 blocks =
// exactly 1 block/CU (fixes R5's 1.5-round quantization). B-LDS holds 256 QK
// rows + 128 V rows = 384; LDS = 2*(256+384)*64*2B = 160 KB (max, R2-proven).
// 8 waves as 2M x 4N: wave = 128x96 QK+V combined; 28 ds_reads / 96 MFMA per
// K-tile (0.29/MFMA). 4 phases/K-tile (R5's schedule, per-block-eff proven):
// (h0,k0)+stage6, (h1,k0)+stage4, (h0,k1), (h1,k1)+vmcnt(0). XCD mapping =
// R1-style m-slice (4 m-tiles = 2 MB A per XCD -> L2-resident, FETCH ~49MB).
// VGPR: acc 192 + frags ~40 ~= 248; __launch_bounds__(512,2) enforces <=256.
__global__ __launch_bounds__(512, 2)
void k_gemmQKV(const ushort* __restrict__ A, const ushort* __restrict__ W,
               const float* __restrict__ bq, const float* __restrict__ bk,
               const float* __restrict__ bv,
               ushort* __restrict__ oQ, ushort* __restrict__ oK,
               ushort* __restrict__ oV) {
  __shared__ ushort As[2][256 * 64];   // 64 KB
  __shared__ ushort Bs[2][384 * 64];   // 96 KB  (rows 0-255 QK, 256-383 V)
  const int tid = threadIdx.x;
  const int wave = tid >> 6, lane = tid & 63;
  const int col = lane & 15, quad = lane >> 4;
  const int id = blockIdx.x;
  const int xcd = id & 7, idx = id >> 3;        // 32 idx per XCD
  const int m0 = (xcd * 4 + (idx & 3)) * 256;   // 4 m-tiles per XCD (2 MB A slice)
  const int nb = idx >> 2;                      // 0..7
  const int wm = (wave >> 2) * 128;
  const int wn = (wave & 3) * 64;               // QK n-offset (wave covers 64 of 256)
  const int wnv = (wave & 3) * 32;              // V n-offset (wave covers 32 of 128)
  const bool matQ = (nb < 4);

  // staging: unit = 8 rows x 128 B; global chunk pre-XOR'd by row (R1-proven)
  const int grow = lane >> 3;                 // 0..7
  const int gchunk = ((lane & 7) ^ grow) * 8; // swizzled k-offset (elements)
  const int cswz = col & 7;
  const ushort* Ag = A + (size_t)(m0 + wave * 32 + grow) * 1024 + gchunk;

  // B-unit u (0..5): rows wave*48 + u*8. <256 -> Wqk[nb*256 + r], else Wv rows
  // 2048 + nb*128 + (r-256). Called with constexpr u only (stays in regs).
  auto bptr = [&](int u) {
    const int br = wave * 48 + u * 8;
    const int wr = (br < 256) ? (nb * 256 + br + grow)
                              : (2048 + nb * 128 + (br - 256) + grow);
    return W + (size_t)wr * 1024 + gchunk;
  };

  f32x4 aq[8][4] = {};   // QK accumulator (swapped, C^T)
  f32x4 av[8][2] = {};   // V accumulator (unswapped)
  bf16x8 bfr[4], bfv[2];

  auto stage6 = [&](int t1) {   // A units 0-3 + B units 0-1
    const int buf = t1 & 1;
    const int ks = t1 * 64;
#pragma unroll
    for (int u = 0; u < 4; ++u)
      gload_lds16(Ag + (size_t)u * 8 * 1024 + ks, &As[buf][(wave * 32 + u * 8) * 64]);
#pragma unroll
    for (int u = 0; u < 2; ++u)
      gload_lds16(bptr(u) + ks, &Bs[buf][(wave * 48 + u * 8) * 64]);
  };
  auto stage4 = [&](int t1) {   // B units 2-5
    const int buf = t1 & 1;
    const int ks = t1 * 64;
#pragma unroll
    for (int u = 2; u < 6; ++u)
      gload_lds16(bptr(u) + ks, &Bs[buf][(wave * 48 + u * 8) * 64]);
  };

  // one phase: ds_reads -> (stage) -> barrier -> lgkm drain -> 24 MFMA -> barrier
  auto phase = [&](int p, int h, int kk, bool rdB, int dr, auto stg) {
    const int ko = ((kk * 4 + quad) ^ cswz) * 8;
    bf16x8 af[4];
#pragma unroll
    for (int i = 0; i < 4; ++i)
      af[i] = ldsFrag(&As[p][(wm + h * 64 + i * 16 + col) * 64 + ko]);
    if (rdB) {
#pragma unroll
      for (int j = 0; j < 4; ++j)
        bfr[j] = ldsFrag(&Bs[p][(wn + j * 16 + col) * 64 + ko]);
#pragma unroll
      for (int j = 0; j < 2; ++j)
        bfv[j] = ldsFrag(&Bs[p][(256 + wnv + j * 16 + col) * 64 + ko]);
    }
    stg();
    SBAR();
    asm volatile("s_waitcnt lgkmcnt(0)" ::: "memory");
    __builtin_amdgcn_sched_barrier(0);
    __builtin_amdgcn_s_setprio(1);
#pragma unroll
    for (int i = 0; i < 4; ++i)
#pragma unroll
      for (int j = 0; j < 4; ++j)
        aq[h * 4 + i][j] = mfma16(bfr[j], af[i], aq[h * 4 + i][j]);   // C^T
#pragma unroll
    for (int i = 0; i < 4; ++i)
#pragma unroll
      for (int j = 0; j < 2; ++j)
        av[h * 4 + i][j] = mfma16(af[i], bfv[j], av[h * 4 + i][j]);
    __builtin_amdgcn_s_setprio(0);
    if (dr) { asm volatile("s_waitcnt vmcnt(0)" ::: "memory"); }
    SBAR();
  };

  // prologue: stage tile 0, drain, barrier
  stage6(0); stage4(0);
  asm volatile("s_waitcnt vmcnt(0)" ::: "memory");
  SBAR();

  for (int t = 0; t < 16; ++t) {
    const int p = t & 1;
    const bool st = (t < 15);
    phase(p, 0, 0, true,  0,  [&] { if (st) stage6(t + 1); });
    phase(p, 1, 0, false, 0,  [&] { if (st) stage4(t + 1); });
    phase(p, 0, 1, true,  0,  [&] {});
    phase(p, 1, 1, false, st ? 1 : 0, [&] {});
  }

  // ---- QK epilogue (swapped C^T; R5-proven index form) ----
  {
    ushort* dst = matQ ? oQ : oK;
    const float* bias = matQ ? bq : bk;
    const float sc = matQ ? QSCALE : 1.0f;
#pragma unroll
    for (int h = 0; h < 2; ++h)
#pragma unroll
      for (int j = 0; j < 4; ++j) {
        const int nl = (nb & 3) * 256 + wn + j * 16 + quad * 4;
        const int hh = nl >> 6, dh0 = nl & 63;
        const float4 bb = *(const float4*)&bias[nl];
#pragma unroll
        for (int i = 0; i < 4; ++i) {
          const int m = m0 + wm + h * 64 + i * 16 + col;
          const int b = m >> 11, t = m & 2047;
          ushort4 pk;
          pk.x = f2b((aq[h * 4 + i][j][0] + bb.x) * sc);
          pk.y = f2b((aq[h * 4 + i][j][1] + bb.y) * sc);
          pk.z = f2b((aq[h * 4 + i][j][2] + bb.z) * sc);
          pk.w = f2b((aq[h * 4 + i][j][3] + bb.w) * sc);
          *(ushort4*)&dst[(((size_t)(b * 16 + hh) * 2048) + t) * 64 + dh0] = pk;
        }
      }
  }
  // ---- V epilogue (unswapped, transposed store; R5-proven index form) ----
  {
#pragma unroll
    for (int h = 0; h < 2; ++h)
#pragma unroll
      for (int j = 0; j < 2; ++j) {
        const int nl = nb * 128 + wnv + j * 16 + col;
        const int hh = nl >> 6, dh = nl & 63;
        const float bn = bv[nl];
#pragma unroll
        for (int i = 0; i < 4; ++i) {
          const int mBase = m0 + wm + h * 64 + i * 16 + quad * 4;
          const int b = mBase >> 11, t = mBase & 2047;
          ushort4 pk;
          pk.x = f2b(av[h * 4 + i][j][0] + bn);
          pk.y = f2b(av[h * 4 + i][j][1] + bn);
          pk.z = f2b(av[h * 4 + i][j][2] + bn);
          pk.w = f2b(av[h * 4 + i][j][3] + bn);
          *(ushort4*)&oV[(((size_t)(b * 16 + hh) * 64) + dh) * 2048 + t] = pk;
        }
      }
  }
}

// ---------------- out-proj GEMM (R1-verified structure, unchanged) ----------------
// 128x256 tile, BK=64, 512 threads (8 waves, 2M x 4N), TRIPLE-buffered LDS
// (144 KB), 2 phases per K-tile, counted vmcnt(6), setprio, XOR swizzle.
// Swapped-operand MFMA (computes C^T) for vectorized fp32 stores. 256 blocks.
__global__ __launch_bounds__(512, 2)
void k_gemmP(const ushort* __restrict__ A, const ushort* __restrict__ W,
             const float* __restrict__ b0, float* __restrict__ outF) {
  __shared__ ushort As[3 * 128 * 64];   // 48 KB, tile t in buf t%3
  __shared__ ushort Bs[3 * 256 * 64];   // 96 KB
  const int tid = threadIdx.x;
  const int wave = tid >> 6, lane = tid & 63;
  const int col = lane & 15, quad = lane >> 4;
  const int id = blockIdx.x;
  const int s_ = id >> 3;
  const int m0 = ((id & 7) * 8 + (s_ & 7)) * 128;   // 64 m-tiles, 8 per XCD
  const int n0 = (s_ >> 3) * 256;
  const int wm = (wave >> 2) * 64, wn = (wave & 3) * 64;
  f32x4 acc[4][4] = {};

  const int grow = lane >> 3;                 // 0..7
  const int gchunk = ((lane & 7) ^ grow) * 8; // swizzled k-offset (elements)
  const int cswz = col & 7;
  const ushort* Ag = A + (size_t)(m0 + wave * 16 + grow) * 1024 + gchunk;
  const ushort* Wg = W + (size_t)(n0 + wave * 32 + grow) * 1024 + gchunk;
  ushort* AsW = &As[wave * 1024];
  ushort* BsW = &Bs[wave * 2048];

  auto stageA = [&](int ks, int sb) {
    gload_lds16(Ag + ks,        AsW + sb * 8192);
    gload_lds16(Ag + ks + 8192, AsW + sb * 8192 + 512);
  };
  auto stageBh = [&](int ks, int sb, int h) {   // h = 0/1: 16-row half of B stripe
    const ushort* sp = Wg + ks + h * 16384;
    ushort* dp = BsW + sb * 16384 + h * 1024;
    gload_lds16(sp,        dp);
    gload_lds16(sp + 8192, dp + 512);
  };

  auto phase = [&](int cur, int kk, auto stagef) {
    const int ko = ((kk * 4 + quad) ^ cswz) * 8;
    const ushort* Ab = &As[cur * 8192];
    const ushort* Bb = &Bs[cur * 16384];
    bf16x8 af[4], bfr[4];
#pragma unroll
    for (int i = 0; i < 4; ++i)
      af[i] = ldsFrag(&Ab[(wm + i * 16 + col) * 64 + ko]);
#pragma unroll
    for (int j = 0; j < 4; ++j)
      bfr[j] = ldsFrag(&Bb[(wn + j * 16 + col) * 64 + ko]);
    stagef();
    SBAR();
    __builtin_amdgcn_s_setprio(1);
#pragma unroll
    for (int i = 0; i < 4; ++i)
#pragma unroll
      for (int j = 0; j < 4; ++j)
        acc[i][j] = mfma16(bfr[j], af[i], acc[i][j]);   // D = C^T tile
    __builtin_amdgcn_s_setprio(0);
  };

  // prologue: stage tiles 0,1 (12 loads); wait tile0 (6 may stay in flight)
  stageA(0, 0);  stageBh(0, 0, 0);  stageBh(0, 0, 1);
  stageA(64, 1); stageBh(64, 1, 0); stageBh(64, 1, 1);
  asm volatile("s_waitcnt vmcnt(6)" ::: "memory");
  SBAR();

  int r0 = 0, r1 = 1, r2 = 2;                // r0 = buf of tile t
  for (int t = 0; t < 14; ++t) {
    const int ks = (t + 2) * 64;
    phase(r0, 0, [&] { stageA(ks, r2); stageBh(ks, r2, 0); });
    SBAR();
    phase(r0, 1, [&] { stageBh(ks, r2, 1); });
    asm volatile("s_waitcnt vmcnt(6)" ::: "memory");
    SBAR();
    const int tmp = r0; r0 = r1; r1 = r2; r2 = tmp;
  }
  phase(r0, 0, [&] {});
  SBAR();
  phase(r0, 1, [&] {});
  asm volatile("s_waitcnt vmcnt(0)" ::: "memory");
  SBAR();
  phase(r1, 0, [&] {});
  SBAR();
  phase(r1, 1, [&] {});

  // swapped: lane holds n = n0+wn+j*16+quad*4+r, m = m0+wm+i*16+col
#pragma unroll
  for (int j = 0; j < 4; ++j) {
    const int nb = n0 + wn + j * 16 + quad * 4;
    const float4 bb = *(const float4*)&b0[nb];
#pragma unroll
    for (int i = 0; i < 4; ++i) {
      const int m = m0 + wm + i * 16 + col;
      float4 v;
      v.x = acc[i][j][0] + bb.x;
      v.y = acc[i][j][1] + bb.y;
      v.z = acc[i][j][2] + bb.z;
      v.w = acc[i][j][3] + bb.w;
      *(float4*)&outF[(size_t)m * 1024 + nb] = v;
    }
  }
}

// ---------------- Flash attention (causal, base-2, no-max softmax) ----------------
// Q (pre-scaled), K: [BH,T,64]; Vt: [BH,64,T]; AO: [M,1024] bf16.
// One 256-q-row tile per block. Grid 512, LDS 69 KB, 2 blocks/CU.
// Block pairing: ids (x, x+256) get t + t' = 7 (balanced per-CU work).
__global__ __launch_bounds__(512, 4)
void k_attn(const ushort* __restrict__ Q, const ushort* __restrict__ K,
            const ushort* __restrict__ Vt, ushort* __restrict__ AO) {
  __shared__ ushort Ks[2 * 4096];          // [buf][kv 64][dh 64]
  __shared__ ushort Vs[2 * 4096];          // [buf][dh 64][kv 64]
  __shared__ ushort Os[512];               // ones A-tile: row0 = 1.0, rest 0
  __shared__ ushort Ps[16 * 16 * 72];      // [strip 16][q 16][kv 64 + pad]
  const int tid = threadIdx.x;
  const int wave = tid >> 6, lane = tid & 63;
  const int col = lane & 15, quad = lane >> 4;
  const int id = blockIdx.x;
  const int bh = (id & 7) * 8 + ((id >> 3) & 7);
  const int g = id >> 6;                   // 0..7
  const int t = (id < 256) ? (7 - g) : (g - 4);   // q-tile index 0..7
  const int q0 = t * 256;
  const ushort* Qg = Q + (size_t)bh * 2048 * 64;
  const ushort* Kg = K + (size_t)bh * 2048 * 64;
  const ushort* Vg = Vt + (size_t)bh * 64 * 2048;

  // init ones tile (A-operand: row0 = 1.0 across all k)
  if (tid < 128) {
    const ushort one = 0x3F80;
    ushort4 zv;
    if (tid < 8) { zv.x = one; zv.y = one; zv.z = one; zv.w = one; }
    else         { zv.x = 0;   zv.y = 0;   zv.z = 0;   zv.w = 0;   }
    *(ushort4*)&Os[tid * 4] = zv;
  }

  const int grow = lane >> 3;
  const int gchunk = ((lane & 7) ^ grow) * 8;
  const int cswz = col & 7;
  ushort* Pw0 = &Ps[((wave * 2 + 0) * 16 + col) * 72];
  ushort* Pw1 = &Ps[((wave * 2 + 1) * 16 + col) * 72];

  // Q B-frags for this wave's two strips
  bf16x8 qf[2][2];
#pragma unroll
  for (int s = 0; s < 2; ++s) {
    const ushort* p = Qg + (q0 + wave * 32 + s * 16 + col) * 64 + quad * 8;
    qf[s][0] = __builtin_bit_cast(bf16x8, *(const uint4*)p);
    qf[s][1] = __builtin_bit_cast(bf16x8, *(const uint4*)(p + 32));
  }

  f32x4 o[2][4] = {};
  f32x4 la[2] = {};

  const ushort* kPtr = Kg + (wave * 8 + grow) * 64 + gchunk;
  const ushort* vPtr = Vg + (size_t)(wave * 8 + grow) * 2048 + gchunk;

  auto stage = [&](auto bufc) {
    constexpr int BUF = decltype(bufc)::value;
    gload_lds16(kPtr, &Ks[BUF * 4096 + wave * 512]);
    gload_lds16(vPtr, &Vs[BUF * 4096 + wave * 512]);
    kPtr += 64 * 64;
    vPtr += 64;
  };

  auto step = [&](auto bufc, auto maskc, int j0) {
    constexpr int BUF = decltype(bufc)::value;
    constexpr bool MASKED = (decltype(maskc)::value != 0);
    const ushort* Kb = &Ks[BUF * 4096];
    const ushort* Vb = &Vs[BUF * 4096];
    bf16x8 kf[4][2];
#pragma unroll
    for (int i = 0; i < 4; ++i) {
      kf[i][0] = ldsFrag(&Kb[(i * 16 + col) * 64 + (((0 * 4 + quad) ^ cswz) * 8)]);
      kf[i][1] = ldsFrag(&Kb[(i * 16 + col) * 64 + (((1 * 4 + quad) ^ cswz) * 8)]);
    }
#pragma unroll
    for (int s = 0; s < 2; ++s) {
      ushort* Pw = s ? Pw1 : Pw0;
      const int dlim = MASKED ? (q0 + wave * 32 + s * 16 + col - j0 - quad * 4) : 0;
#pragma unroll
      for (int i = 0; i < 4; ++i) {
        f32x4 z = {0.f, 0.f, 0.f, 0.f};
        f32x4 sv = mfma16(kf[i][0], qf[s][0], z);
        sv = mfma16(kf[i][1], qf[s][1], sv);
        if (MASKED) {
#pragma unroll
          for (int r = 0; r < 4; ++r)
            if (i * 16 + r > dlim) sv[r] = -1e30f;
        }
        f32x4 pv;
#pragma unroll
        for (int r = 0; r < 4; ++r) pv[r] = __builtin_amdgcn_exp2f(sv[r]);
        uint2 pk;
        pk.x = pkbf(pv[0], pv[1]);
        pk.y = pkbf(pv[2], pv[3]);
        *(uint2*)&Pw[i * 16 + quad * 4] = pk;
      }
    }
    // PV: O^T[dh][q] += Vt * P^T ; l via ones-row MFMA
    bf16x8 osf = ldsFrag(&Os[col * 32 + quad * 8]);
#pragma unroll
    for (int c = 0; c < 2; ++c) {
      bf16x8 pb0 = ldsFrag(&Pw0[c * 32 + quad * 8]);
      bf16x8 pb1 = ldsFrag(&Pw1[c * 32 + quad * 8]);
      la[0] = mfma16(osf, pb0, la[0]);
      la[1] = mfma16(osf, pb1, la[1]);
#pragma unroll
      for (int i = 0; i < 4; ++i) {
        bf16x8 vf = ldsFrag(&Vb[(i * 16 + col) * 64 + (((c * 4 + quad) ^ cswz) * 8)]);
        o[0][i] = mfma16(vf, pb0, o[0][i]);
        o[1][i] = mfma16(vf, pb1, o[1][i]);
      }
    }
  };

  __syncthreads();                 // Os init visible
  stage(IC<0>{});                  // kv tile 0
  for (int it2 = 0; it2 < 2 * t; ++it2) {   // 4t full tiles
    __syncthreads();
    stage(IC<1>{});
    step(IC<0>{}, IC<0>{}, 0);
    __syncthreads();
    stage(IC<0>{});
    step(IC<1>{}, IC<0>{}, 0);
  }
  // 4 diagonal tiles (kv = q0 .. q0+256), parities 0,1,0,1
  __syncthreads();
  stage(IC<1>{});
  step(IC<0>{}, IC<1>{}, q0);
  __syncthreads();
  stage(IC<0>{});
  if (wave >= 2) step(IC<1>{}, IC<1>{}, q0 + 64);
  __syncthreads();
  stage(IC<1>{});
  if (wave >= 4) step(IC<0>{}, IC<1>{}, q0 + 128);
  __syncthreads();
  if (wave >= 6) step(IC<1>{}, IC<1>{}, q0 + 192);

  // epilogue: O^T C-layout: row dh = i*16 + quad*4 + r, col q = col
  const float invs[2] = {1.0f / __shfl(la[0][0], col), 1.0f / __shfl(la[1][0], col)};
  const int b = bh >> 4, h = bh & 15;
#pragma unroll
  for (int s = 0; s < 2; ++s) {
    const float inv = invs[s];
    const int tq = q0 + wave * 32 + s * 16 + col;
    ushort* dst = AO + (size_t)(b * 2048 + tq) * 1024 + h * 64;
#pragma unroll
    for (int i = 0; i < 4; ++i) {
      f32x4 v = o[s][i];
      ushort4 pk;
      pk.x = f2b(v[0] * inv);
      pk.y = f2b(v[1] * inv);
      pk.z = f2b(v[2] * inv);
      pk.w = f2b(v[3] * inv);
      *(ushort4*)&dst[i * 16 + quad * 4] = pk;
    }
  }
}

// ---------------- launch ----------------
extern "C" void kernel_launch(void* const* d_in, const int* in_sizes, int n_in,
                              void* d_out, int out_size, void* d_ws, size_t ws_size,
                              hipStream_t stream) {
  const float* x  = (const float*)d_in[0];
  const float* Wq = (const float*)d_in[1];
  const float* bq = (const float*)d_in[2];
  const float* Wk = (const float*)d_in[3];
  const float* bk = (const float*)d_in[4];
  const float* Wv = (const float*)d_in[5];
  const float* bv = (const float*)d_in[6];
  const float* Wo = (const float*)d_in[7];
  const float* bo = (const float*)d_in[8];
  float* out = (float*)d_out;

  char* ws = (char*)d_ws;
  ushort* xb    = (ushort*)ws;                                 // 16 MB
  ushort* Wcat  = (ushort*)(ws + (size_t)16 * 1024 * 1024);    // 8 MB (Wq|Wk|Wv|Wo)
  ushort* Wob   = Wcat + (size_t)3 * 1024 * 1024;
  ushort* Qh    = (ushort*)(ws + (size_t)24 * 1024 * 1024);    // 16 MB
  ushort* Kh    = Qh + (size_t)8192 * 1024;
  ushort* Vt    = Kh + (size_t)8192 * 1024;
  ushort* AO    = Vt + (size_t)8192 * 1024;

  // fused converts: x (8192 blocks) + 4 weights (4096 blocks)
  k_cvtAll<<<12288, 256, 0, stream>>>((const float4*)x,
                                      (const float4*)Wq, (const float4*)Wk,
                                      (const float4*)Wv, (const float4*)Wo,
                                      (ushort4*)xb, (ushort4*)Wcat);

  // fused QKV GEMM: 256x(256 QK + 128 V) tiles, 32 x 8 = 256 blocks = 1 round
  k_gemmQKV<<<256, 512, 0, stream>>>(xb, Wcat, bq, bk, bv, Qh, Kh, Vt);

  // attention: 512 blocks (bh x q-tile), 2 blocks/CU
  k_attn<<<512, 512, 0, stream>>>(Qh, Kh, Vt, AO);

  // out-projection: N = 1024, 256 blocks, fp32 out (R1-verified kernel)
  k_gemmP<<<256, 512, 0, stream>>>(AO, Wob, bo, out);
}